// Round 2
// baseline (489.312 us; speedup 1.0000x reference)
//
#include <hip/hip_runtime.h>
#include <cmath>

#define NN 200000
#define NE 600000

typedef __bf16 bf16x8 __attribute__((ext_vector_type(8)));
typedef float f32x4 __attribute__((ext_vector_type(4)));

#define LOG2E 1.44269504088896340736f
__device__ __forceinline__ float fexp2(float x) { return __builtin_amdgcn_exp2f(x); }
__device__ __forceinline__ float frcp(float x) { return __builtin_amdgcn_rcpf(x); }
__device__ __forceinline__ float sigm(float v) { return frcp(1.0f + fexp2(-LOG2E * v)); }
__device__ __forceinline__ float ftanh(float v) {
  float t = fexp2(-2.0f * LOG2E * fabsf(v));
  float r = (1.0f - t) * frcp(1.0f + t);
  return __builtin_copysignf(r, v);
}
__device__ __forceinline__ float eluf(float v) { return v > 0.0f ? v : fexp2(LOG2E * v) - 1.0f; }

__device__ __forceinline__ unsigned short bfr(float f) {  // f32 -> bf16 RNE
  unsigned u = __float_as_uint(f);
  u += 0x7FFFu + ((u >> 16) & 1u);
  return (unsigned short)(u >> 16);
}
__device__ __forceinline__ void bsplit(float v, unsigned short& hi, unsigned short& lo) {
  unsigned short h = bfr(v);
  float hf = __uint_as_float(((unsigned)h) << 16);
  hi = h;
  lo = bfr(v - hf);
}

// ---------------- ws layout (float offsets) ----------------
// x1 [25,600,000] @0 ; deg(int)[200,000] @25,600,000 ; rwt0[128] @25,800,000 ;
// rwh0[384] @25,800,128 ; packed bf16 weight frags (shorts) @float 25,800,512:
//   w0ph 49152 | w0pl 49152 | w1ph 16384 | w1pl 16384 | w2ph 98304 | w2pl 98304

__global__ __launch_bounds__(256) void hist_kernel(const int* __restrict__ dst,
                                                   int* __restrict__ deg) {
  int e = blockIdx.x * 256 + threadIdx.x;
  if (e < NE) atomicAdd(&deg[dst[e]], 1);
}

// one wave per row, coalesced float2 loads + shuffle reduce (512 rows total)
__global__ __launch_bounds__(256) void prep_kernel(const float* __restrict__ attw0,
                                                   const float* __restrict__ whh0,
                                                   float* __restrict__ rwt0,
                                                   float* __restrict__ rwh0) {
  int gw = blockIdx.x * 4 + (threadIdx.x >> 6);  // 0..511
  int lane = threadIdx.x & 63;
  const float* row = (gw < 128) ? (attw0 + (size_t)gw * 128)
                                : (whh0 + (size_t)(gw - 128) * 128);
  float2 v = ((const float2*)row)[lane];
  float a = v.x + v.y;
#pragma unroll
  for (int o = 1; o < 64; o <<= 1) a += __shfl_xor(a, o, 64);
  if (lane == 0) {
    if (gw < 128) rwt0[gw] = a;
    else rwh0[gw - 128] = a;
  }
}

// Pack weights into MFMA B-fragment order, split hi/lo bf16:
// frag[((nt*4+ks)*64+lane)*8 + j] = W[nt*16+(lane&15)][ks*32+(lane>>4)*8+j]
__global__ __launch_bounds__(256) void pack_kernel(
    const float* __restrict__ wih0, const float* __restrict__ tw1,
    const float* __restrict__ wih1, const float* __restrict__ whh1,
    unsigned short* __restrict__ w0ph, unsigned short* __restrict__ w0pl,
    unsigned short* __restrict__ w1ph, unsigned short* __restrict__ w1pl,
    unsigned short* __restrict__ w2ph, unsigned short* __restrict__ w2pl) {
  int g = blockIdx.x * 256 + threadIdx.x;  // one 8-element lane-frag
  unsigned short *PH, *PL;
  const float* row;
  int l;
  if (g < 6144) { l = g; PH = w0ph; PL = w0pl; }
  else if (g < 8192) { l = g - 6144; PH = w1ph; PL = w1pl; }
  else if (g < 20480) { l = g - 8192; PH = w2ph; PL = w2pl; }
  else return;
  int lane = l & 63, ks = (l >> 6) & 3, nt = l >> 8;
  int n = nt * 16 + (lane & 15);
  int k0 = ks * 32 + (lane >> 4) * 8;
  if (g < 6144) row = wih0 + n * 128;
  else if (g < 8192) row = tw1 + n * 128;
  else row = (n < 384) ? wih1 + n * 128 : whh1 + (n - 384) * 128;
  unsigned uh[4], ul[4];
  for (int p = 0; p < 4; p++) {
    unsigned short ah, al, bh, bl;
    bsplit(row[k0 + 2 * p], ah, al);
    bsplit(row[k0 + 2 * p + 1], bh, bl);
    uh[p] = (unsigned)ah | ((unsigned)bh << 16);
    ul[p] = (unsigned)al | ((unsigned)bl << 16);
  }
  *(uint4*)&PH[l * 8] = make_uint4(uh[0], uh[1], uh[2], uh[3]);
  *(uint4*)&PL[l * 8] = make_uint4(ul[0], ul[1], ul[2], ul[3]);
}

#define MFMA3(accv, ah, al, bh, bl)                                          \
  accv = __builtin_amdgcn_mfma_f32_16x16x32_bf16(ah, bh, accv, 0, 0, 0);     \
  accv = __builtin_amdgcn_mfma_f32_16x16x32_bf16(ah, bl, accv, 0, 0, 0);     \
  accv = __builtin_amdgcn_mfma_f32_16x16x32_bf16(al, bh, accv, 0, 0, 0);

// ---------------- layer 0: M=64 nodes/block, 512 threads (8 waves) ----------------
__global__ __launch_bounds__(512, 4) void layer0_kernel(
    const float* __restrict__ x, const float* __restrict__ tb0,
    const unsigned short* __restrict__ w0ph, const unsigned short* __restrict__ w0pl,
    const float* __restrict__ bih0, const float* __restrict__ bhh0,
    const float* __restrict__ rwt0, const float* __restrict__ rwh0,
    const int* __restrict__ deg, float* __restrict__ x1) {
  __shared__ float s_lds[64];
  __shared__ float deg_lds[64];
  __shared__ unsigned short csh[64 * 136];
  __shared__ unsigned short csl[64 * 136];

  const int tid = threadIdx.x;
  const int lane = tid & 63;
  const int wv = tid >> 6;  // 0..7
  const int n0 = blockIdx.x * 64;

  if (tid < 64) deg_lds[tid] = (float)deg[n0 + tid];

  // s_m = rowsum(x[m])
  {
    int m = tid >> 3, c = (tid & 7) * 16;
    const float4* xr = (const float4*)(x + (size_t)(n0 + m) * 128 + c);
    float a = 0.f;
#pragma unroll
    for (int q = 0; q < 4; q++) { float4 v = xr[q]; a += v.x + v.y + v.z + v.w; }
#pragma unroll
    for (int o = 1; o < 8; o <<= 1) a += __shfl_xor(a, o, 64);
    if ((tid & 7) == 0) s_lds[m] = a;
  }
  __syncthreads();

  // cs0[m][k] = elu(s_m * rwt0[k] + tb0[k]) -> split bf16 LDS
  {
    int m = tid >> 3, c0 = (tid & 7) * 16;
    float s = s_lds[m];
#pragma unroll
    for (int q = 0; q < 4; q++) {
      int k = c0 + q * 4;
      unsigned short h0, l0, h1, l1, h2, l2, h3, l3;
      bsplit(eluf(fmaf(s, rwt0[k], tb0[k])), h0, l0);
      bsplit(eluf(fmaf(s, rwt0[k + 1], tb0[k + 1])), h1, l1);
      bsplit(eluf(fmaf(s, rwt0[k + 2], tb0[k + 2])), h2, l2);
      bsplit(eluf(fmaf(s, rwt0[k + 3], tb0[k + 3])), h3, l3);
      *(uint2*)&csh[m * 136 + k] =
          make_uint2((unsigned)h0 | ((unsigned)h1 << 16), (unsigned)h2 | ((unsigned)h3 << 16));
      *(uint2*)&csl[m * 136 + k] =
          make_uint2((unsigned)l0 | ((unsigned)l1 << 16), (unsigned)l2 | ((unsigned)l3 << 16));
    }
  }
  __syncthreads();

  // gi = cs0 @ wih0^T via split-bf16 MFMA; per wave: 4 m-tiles x 3 gate-tiles
  const int mrow = lane & 15;
  const int kq = (lane >> 4) * 8;
  const int quad = lane >> 4;
  f32x4 acc[4][3] = {};
#pragma unroll
  for (int ks = 0; ks < 4; ks++) {
    bf16x8 ah[4], al[4];
#pragma unroll
    for (int mt = 0; mt < 4; mt++) {
      ah[mt] = *(const bf16x8*)&csh[(mt * 16 + mrow) * 136 + ks * 32 + kq];
      al[mt] = *(const bf16x8*)&csl[(mt * 16 + mrow) * 136 + ks * 32 + kq];
    }
#pragma unroll
    for (int g = 0; g < 3; g++) {
      int nt = g * 8 + wv;
      size_t base = (size_t)((nt * 4 + ks) * 64 + lane) * 8;
      bf16x8 bh = *(const bf16x8*)&w0ph[base];
      bf16x8 bl = *(const bf16x8*)&w0pl[base];
#pragma unroll
      for (int mt = 0; mt < 4; mt++) { MFMA3(acc[mt][g], ah[mt], al[mt], bh, bl); }
    }
  }

  // GRU epilogue (h = s broadcast, gh = s*rwh0 + bhh0), scale by deg
  const int j = wv * 16 + mrow;
  float bir = bih0[j], biz = bih0[j + 128], bin_ = bih0[j + 256];
  float bhr = bhh0[j], bhz = bhh0[j + 128], bhn = bhh0[j + 256];
  float rwr = rwh0[j], rwz = rwh0[j + 128], rwn = rwh0[j + 256];
#pragma unroll
  for (int mt = 0; mt < 4; mt++) {
#pragma unroll
    for (int reg = 0; reg < 4; reg++) {
      int m = mt * 16 + quad * 4 + reg;
      float s = s_lds[m];
      float dd = deg_lds[m];
      float gir = acc[mt][0][reg] + bir;
      float giz = acc[mt][1][reg] + biz;
      float gin = acc[mt][2][reg] + bin_;
      float ghr = fmaf(s, rwr, bhr);
      float ghz = fmaf(s, rwz, bhz);
      float ghn = fmaf(s, rwn, bhn);
      float r = sigm(gir + ghr);
      float z = sigm(giz + ghz);
      float nn2 = ftanh(fmaf(r, ghn, gin));
      x1[(size_t)(n0 + m) * 128 + j] = dd * ((1.f - z) * nn2 + z * s);
    }
  }
}

// ---------------- layer 1: M=128 nodes/block, 1024 threads (16 waves) ----------------
// 16 waves = 4 m-groups (32 rows) x 4 n-groups (32 gate-cols). Gate-merged accs:
// r and z accumulate BOTH wih and whh GEMMs into the same C regs (GRU adds them
// elementwise anyway); only n keeps gin/ghn separate -> 64 acc regs + acc1(16, dead
// before phase B). launch_bounds(1024) forces <=128 regs -> 4 waves/SIMD resident.
// LDS: hh,hl,ch,cl = 4 * 128*136 shorts = 139264 B dynamic (1 block/CU).
__global__ __launch_bounds__(1024) void layer1_kernel(
    const float* __restrict__ x1, const float* __restrict__ tb1,
    const unsigned short* __restrict__ w1ph, const unsigned short* __restrict__ w1pl,
    const unsigned short* __restrict__ w2ph, const unsigned short* __restrict__ w2pl,
    const float* __restrict__ bih1, const float* __restrict__ bhh1,
    const int* __restrict__ deg, float* __restrict__ out) {
  extern __shared__ unsigned short smem[];
  unsigned short* hh = smem;            // 128*136 = 17408 shorts
  unsigned short* hl = smem + 17408;
  unsigned short* ch = smem + 34816;
  unsigned short* cl = smem + 52224;    // total 69632 shorts = 139264 B
  __shared__ float deg_lds[128];

  const int tid = threadIdx.x;
  const int lane = tid & 63;
  const int wv = tid >> 6;   // 0..15
  const int mg = wv >> 2;    // 0..3 -> rows [mg*32, mg*32+32)
  const int ng = wv & 3;     // 0..3 -> gate cols [ng*32, ng*32+32)
  const int n0 = blockIdx.x * 128;
  const int mrow = lane & 15;
  const int kq = (lane >> 4) * 8;
  const int quad = lane >> 4;

  if (tid < 128) {
    int node = n0 + tid;
    deg_lds[tid] = (node < NN) ? (float)deg[node] : 0.f;
  }

  // stage h = x1 tile, split bf16 (clamped for tail block)
  {
    int m = tid >> 3, c0 = (tid & 7) * 16;
    int node = n0 + m;
    if (node >= NN) node = NN - 1;
    const float4* xr = (const float4*)(x1 + (size_t)node * 128 + c0);
#pragma unroll
    for (int q = 0; q < 4; q++) {
      float4 v = xr[q];
      unsigned short h0, l0, h1, l1, h2, l2, h3, l3;
      bsplit(v.x, h0, l0); bsplit(v.y, h1, l1);
      bsplit(v.z, h2, l2); bsplit(v.w, h3, l3);
      *(uint2*)&hh[m * 136 + c0 + q * 4] =
          make_uint2((unsigned)h0 | ((unsigned)h1 << 16), (unsigned)h2 | ((unsigned)h3 << 16));
      *(uint2*)&hl[m * 136 + c0 + q * 4] =
          make_uint2((unsigned)l0 | ((unsigned)l1 << 16), (unsigned)l2 | ((unsigned)l3 << 16));
    }
  }
  __syncthreads();

  const int r0 = mg * 32;
  const int c0w = ng * 32;  // col base within a 128-wide gate block

  // Phase A1: acc1 = (h @ tw1^T) cols [c0w, c0w+32)
  f32x4 acc1[2][2] = {};
#pragma unroll
  for (int ks = 0; ks < 4; ks++) {
    bf16x8 xh[2], xl[2];
#pragma unroll
    for (int mt = 0; mt < 2; mt++) {
      xh[mt] = *(const bf16x8*)&hh[(r0 + mt * 16 + mrow) * 136 + ks * 32 + kq];
      xl[mt] = *(const bf16x8*)&hl[(r0 + mt * 16 + mrow) * 136 + ks * 32 + kq];
    }
#pragma unroll
    for (int sub = 0; sub < 2; sub++) {
      int nt = ng * 2 + sub;
      size_t base = (size_t)((nt * 4 + ks) * 64 + lane) * 8;
      bf16x8 bh = *(const bf16x8*)&w1ph[base];
      bf16x8 bl = *(const bf16x8*)&w1pl[base];
#pragma unroll
      for (int mt = 0; mt < 2; mt++) { MFMA3(acc1[mt][sub], xh[mt], xl[mt], bh, bl); }
    }
  }

  // cs = elu(t1 + tb1) -> split bf16 LDS (pair-lane packed b32 stores)
  {
    float tbj[2];
#pragma unroll
    for (int sub = 0; sub < 2; sub++) tbj[sub] = tb1[c0w + sub * 16 + mrow];
#pragma unroll
    for (int mt = 0; mt < 2; mt++) {
#pragma unroll
      for (int sub = 0; sub < 2; sub++) {
#pragma unroll
        for (int reg = 0; reg < 4; reg++) {
          int m = r0 + mt * 16 + quad * 4 + reg;
          unsigned short vh, vl;
          bsplit(eluf(acc1[mt][sub][reg] + tbj[sub]), vh, vl);
          unsigned pv = (unsigned)vh | ((unsigned)vl << 16);
          unsigned pu = __shfl_xor(pv, 1, 64);
          if ((lane & 1) == 0) {
            int jc = c0w + sub * 16 + mrow;  // even here
            unsigned hpack = (pv & 0xFFFFu) | (pu << 16);
            unsigned lpack = (pv >> 16) | (pu & 0xFFFF0000u);
            *(unsigned*)&ch[m * 136 + jc] = hpack;
            *(unsigned*)&cl[m * 136 + jc] = lpack;
          }
        }
      }
    }
  }
  __syncthreads();

  // Phase A2+B: acc2[mt][sub][grp] with grp: 0=r(gi+gh), 1=z(gi+gh), 2=gin, 3=ghn
  f32x4 acc2[2][2][4] = {};
#pragma unroll
  for (int ks = 0; ks < 4; ks++) {
    {
      bf16x8 xh[2], xl[2];
#pragma unroll
      for (int mt = 0; mt < 2; mt++) {
        xh[mt] = *(const bf16x8*)&hh[(r0 + mt * 16 + mrow) * 136 + ks * 32 + kq];
        xl[mt] = *(const bf16x8*)&hl[(r0 + mt * 16 + mrow) * 136 + ks * 32 + kq];
      }
#pragma unroll
      for (int sub = 0; sub < 2; sub++) {
#pragma unroll
        for (int g = 0; g < 3; g++) {  // gh: whh r,z,n
          int nt = 24 + g * 8 + ng * 2 + sub;
          size_t base = (size_t)((nt * 4 + ks) * 64 + lane) * 8;
          bf16x8 bh = *(const bf16x8*)&w2ph[base];
          bf16x8 bl = *(const bf16x8*)&w2pl[base];
          int grp = (g == 2) ? 3 : g;
#pragma unroll
          for (int mt = 0; mt < 2; mt++) { MFMA3(acc2[mt][sub][grp], xh[mt], xl[mt], bh, bl); }
        }
      }
    }
    {
      bf16x8 ah[2], al[2];
#pragma unroll
      for (int mt = 0; mt < 2; mt++) {
        ah[mt] = *(const bf16x8*)&ch[(r0 + mt * 16 + mrow) * 136 + ks * 32 + kq];
        al[mt] = *(const bf16x8*)&cl[(r0 + mt * 16 + mrow) * 136 + ks * 32 + kq];
      }
#pragma unroll
      for (int sub = 0; sub < 2; sub++) {
#pragma unroll
        for (int g = 0; g < 3; g++) {  // gi: wih r,z,n
          int nt = g * 8 + ng * 2 + sub;
          size_t base = (size_t)((nt * 4 + ks) * 64 + lane) * 8;
          bf16x8 bh = *(const bf16x8*)&w2ph[base];
          bf16x8 bl = *(const bf16x8*)&w2pl[base];
#pragma unroll
          for (int mt = 0; mt < 2; mt++) { MFMA3(acc2[mt][sub][g], ah[mt], al[mt], bh, bl); }
        }
      }
    }
  }

  // GRU epilogue + deg scale
  float bir[2], biz[2], bin_[2], bhr[2], bhz[2], bhn[2];
  int jcol[2];
#pragma unroll
  for (int sub = 0; sub < 2; sub++) {
    int j = c0w + sub * 16 + mrow;
    jcol[sub] = j;
    bir[sub] = bih1[j]; biz[sub] = bih1[j + 128]; bin_[sub] = bih1[j + 256];
    bhr[sub] = bhh1[j]; bhz[sub] = bhh1[j + 128]; bhn[sub] = bhh1[j + 256];
  }
#pragma unroll
  for (int mt = 0; mt < 2; mt++) {
#pragma unroll
    for (int reg = 0; reg < 4; reg++) {
      int m = r0 + mt * 16 + quad * 4 + reg;
      int node = n0 + m;
      float dd = deg_lds[m];
#pragma unroll
      for (int sub = 0; sub < 2; sub++) {
        int j = jcol[sub];
        float r = sigm(acc2[mt][sub][0][reg] + bir[sub] + bhr[sub]);
        float z = sigm(acc2[mt][sub][1][reg] + biz[sub] + bhz[sub]);
        float ghn = acc2[mt][sub][3][reg] + bhn[sub];
        float gin = acc2[mt][sub][2][reg] + bin_[sub];
        float nn2 = ftanh(fmaf(r, ghn, gin));
        float hfull = (float)(*(const __bf16*)&hh[m * 136 + j]) +
                      (float)(*(const __bf16*)&hl[m * 136 + j]);
        if (node < NN)
          out[(size_t)node * 128 + j] = dd * ((1.f - z) * nn2 + z * hfull);
      }
    }
  }
}

extern "C" void kernel_launch(void* const* d_in, const int* in_sizes, int n_in,
                              void* d_out, int out_size, void* d_ws, size_t ws_size,
                              hipStream_t stream) {
  const float* x     = (const float*)d_in[0];
  const int*   edge  = (const int*)d_in[1];
  const float* attw0 = (const float*)d_in[4];
  const float* attb0 = (const float*)d_in[5];
  const float* wih0  = (const float*)d_in[6];
  const float* whh0  = (const float*)d_in[7];
  const float* bih0  = (const float*)d_in[8];
  const float* bhh0  = (const float*)d_in[9];
  const float* attw1 = (const float*)d_in[12];
  const float* attb1 = (const float*)d_in[13];
  const float* wih1  = (const float*)d_in[14];
  const float* whh1  = (const float*)d_in[15];
  const float* bih1  = (const float*)d_in[16];
  const float* bhh1  = (const float*)d_in[17];

  float* ws   = (float*)d_ws;
  float* x1   = ws;
  int*   deg  = (int*)(ws + 25600000);
  float* rwt0 = ws + 25800000;
  float* rwh0 = ws + 25800128;
  unsigned short* wp = (unsigned short*)(ws + 25800512);
  unsigned short* w0ph = wp;             // 49152 shorts
  unsigned short* w0pl = wp + 49152;
  unsigned short* w1ph = wp + 98304;     // 16384
  unsigned short* w1pl = wp + 114688;
  unsigned short* w2ph = wp + 131072;    // 98304
  unsigned short* w2pl = wp + 229376;    // end 327680 shorts

  const int* dst = edge + NE;  // edge_index[1]

  static bool attr_done = false;
  if (!attr_done) {
    hipFuncSetAttribute(reinterpret_cast<const void*>(layer1_kernel),
                        hipFuncAttributeMaxDynamicSharedMemorySize, 139264);
    attr_done = true;
  }

  hipMemsetAsync(deg, 0, NN * sizeof(int), stream);
  hist_kernel<<<(NE + 255) / 256, 256, 0, stream>>>(dst, deg);
  prep_kernel<<<128, 256, 0, stream>>>(attw0, whh0, rwt0, rwh0);
  pack_kernel<<<80, 256, 0, stream>>>(wih0, attw1, wih1, whh1,
                                      w0ph, w0pl, w1ph, w1pl, w2ph, w2pl);
  layer0_kernel<<<NN / 64, 512, 0, stream>>>(x, attb0, w0ph, w0pl, bih0, bhh0,
                                             rwt0, rwh0, deg, x1);
  layer1_kernel<<<(NN + 127) / 128, 1024, 139264, stream>>>(
      x1, attb1, w1ph, w1pl, w2ph, w2pl, bih1, bhh1, deg, (float*)d_out);
}

// Round 3
// 473.825 us; speedup vs baseline: 1.0327x; 1.0327x over previous
//
#include <hip/hip_runtime.h>
#include <cmath>

#define NN 200000
#define NE 600000

typedef __bf16 bf16x8 __attribute__((ext_vector_type(8)));
typedef float f32x16 __attribute__((ext_vector_type(16)));

#define LOG2E 1.44269504088896340736f
__device__ __forceinline__ float fexp2(float x) { return __builtin_amdgcn_exp2f(x); }
__device__ __forceinline__ float frcp(float x) { return __builtin_amdgcn_rcpf(x); }
__device__ __forceinline__ float sigm(float v) { return frcp(1.0f + fexp2(-LOG2E * v)); }
__device__ __forceinline__ float ftanh(float v) {
  float t = fexp2(-2.0f * LOG2E * fabsf(v));
  float r = (1.0f - t) * frcp(1.0f + t);
  return __builtin_copysignf(r, v);
}
__device__ __forceinline__ float eluf(float v) { return v > 0.0f ? v : fexp2(LOG2E * v) - 1.0f; }

__device__ __forceinline__ unsigned short bfr(float f) {  // f32 -> bf16 RNE
  unsigned u = __float_as_uint(f);
  u += 0x7FFFu + ((u >> 16) & 1u);
  return (unsigned short)(u >> 16);
}
__device__ __forceinline__ void bsplit(float v, unsigned short& hi, unsigned short& lo) {
  unsigned short h = bfr(v);
  float hf = __uint_as_float(((unsigned)h) << 16);
  hi = h;
  lo = bfr(v - hf);
}

// ---------------- ws layout (float offsets) ----------------
// x1h bf16-frag [25.6M shorts] @0 ; x1l @12,800,000 ; deg(int) @25,600,000 ;
// rwt0[128] @25,800,000 ; rwh0[384] @25,800,128 ; packed weight frags @25,800,512:
//   w0ph 49152 | w0pl 49152 | w1ph 16384 | w1pl 16384 | w2ph 98304 | w2pl 98304
// Frag order (32x32x16): frag[((nt*8+ks)*64+lane)*8+j] = W[nt*32+(lane&31)][ks*16+(lane>>5)*8+j]
// x1 frag: x1?[blk*8192 + ((mt*8+ks)*64+lane)*8+j] = h[blk*64+mt*32+(lane&31)][ks*16+(lane>>5)*8+j]

__global__ __launch_bounds__(256) void hist_kernel(const int* __restrict__ dst,
                                                   int* __restrict__ deg) {
  int e = blockIdx.x * 256 + threadIdx.x;
  if (e < NE) atomicAdd(&deg[dst[e]], 1);
}

// one wave per row, coalesced float2 loads + shuffle reduce (512 rows total)
__global__ __launch_bounds__(256) void prep_kernel(const float* __restrict__ attw0,
                                                   const float* __restrict__ whh0,
                                                   float* __restrict__ rwt0,
                                                   float* __restrict__ rwh0) {
  int gw = blockIdx.x * 4 + (threadIdx.x >> 6);  // 0..511
  int lane = threadIdx.x & 63;
  const float* row = (gw < 128) ? (attw0 + (size_t)gw * 128)
                                : (whh0 + (size_t)(gw - 128) * 128);
  float2 v = ((const float2*)row)[lane];
  float a = v.x + v.y;
#pragma unroll
  for (int o = 1; o < 64; o <<= 1) a += __shfl_xor(a, o, 64);
  if (lane == 0) {
    if (gw < 128) rwt0[gw] = a;
    else rwh0[gw - 128] = a;
  }
}

// Pack weights into 32x32x16 MFMA B-fragment order, split hi/lo bf16.
__global__ __launch_bounds__(256) void pack_kernel(
    const float* __restrict__ wih0, const float* __restrict__ tw1,
    const float* __restrict__ wih1, const float* __restrict__ whh1,
    unsigned short* __restrict__ w0ph, unsigned short* __restrict__ w0pl,
    unsigned short* __restrict__ w1ph, unsigned short* __restrict__ w1pl,
    unsigned short* __restrict__ w2ph, unsigned short* __restrict__ w2pl) {
  int g = blockIdx.x * 256 + threadIdx.x;  // one 8-element lane-frag
  if (g >= 20480) return;
  unsigned short *PH, *PL;
  const float* row;
  int l;
  if (g < 6144) { l = g; PH = w0ph; PL = w0pl; }
  else if (g < 8192) { l = g - 6144; PH = w1ph; PL = w1pl; }
  else { l = g - 8192; PH = w2ph; PL = w2pl; }
  int lane = l & 63, ks = (l >> 6) & 7, nt = l >> 9;
  int n = nt * 32 + (lane & 31);
  int k0 = ks * 16 + (lane >> 5) * 8;
  if (g < 6144) row = wih0 + n * 128;
  else if (g < 8192) row = tw1 + n * 128;
  else row = (n < 384) ? wih1 + n * 128 : whh1 + (n - 384) * 128;
  unsigned uh[4], ul[4];
#pragma unroll
  for (int p = 0; p < 4; p++) {
    unsigned short ah, al, bh, bl;
    bsplit(row[k0 + 2 * p], ah, al);
    bsplit(row[k0 + 2 * p + 1], bh, bl);
    uh[p] = (unsigned)ah | ((unsigned)bh << 16);
    ul[p] = (unsigned)al | ((unsigned)bl << 16);
  }
  *(uint4*)&PH[l * 8] = make_uint4(uh[0], uh[1], uh[2], uh[3]);
  *(uint4*)&PL[l * 8] = make_uint4(ul[0], ul[1], ul[2], ul[3]);
}

#define MFMA3(accv, ah, al, bh, bl)                                          \
  accv = __builtin_amdgcn_mfma_f32_32x32x16_bf16(ah, bh, accv, 0, 0, 0);     \
  accv = __builtin_amdgcn_mfma_f32_32x32x16_bf16(ah, bl, accv, 0, 0, 0);     \
  accv = __builtin_amdgcn_mfma_f32_32x32x16_bf16(al, bh, accv, 0, 0, 0);

// ---------------- layer 0: M=64 nodes/block, 512 threads (8 waves = 2mg x 4cb) ----
__global__ __launch_bounds__(512, 4) void layer0_kernel(
    const float* __restrict__ x, const float* __restrict__ tb0,
    const unsigned short* __restrict__ w0ph, const unsigned short* __restrict__ w0pl,
    const float* __restrict__ bih0, const float* __restrict__ bhh0,
    const float* __restrict__ rwt0, const float* __restrict__ rwh0,
    const int* __restrict__ deg,
    unsigned short* __restrict__ x1h, unsigned short* __restrict__ x1l) {
  __shared__ float s_lds[64];
  __shared__ float deg_lds[64];
  __shared__ unsigned short csh[8192];
  __shared__ unsigned short csl[8192];

  const int tid = threadIdx.x;
  const int lane = tid & 63;
  const int wv = tid >> 6;
  const int mg = wv & 1;
  const int cb = wv >> 1;
  const int n0 = blockIdx.x * 64;

  if (tid < 64) deg_lds[tid] = (float)deg[n0 + tid];

  // s_m = rowsum(x[m])
  {
    int m = tid >> 3, c = (tid & 7) * 16;
    const float4* xr = (const float4*)(x + (size_t)(n0 + m) * 128 + c);
    float a = 0.f;
#pragma unroll
    for (int q = 0; q < 4; q++) { float4 v = xr[q]; a += v.x + v.y + v.z + v.w; }
#pragma unroll
    for (int o = 1; o < 8; o <<= 1) a += __shfl_xor(a, o, 64);
    if ((tid & 7) == 0) s_lds[m] = a;
  }
  __syncthreads();

  // cs0 -> split-bf16 LDS in 32x32 A-frag layout (lane-linear, conflict-free)
  {
    int m = lane, c = wv;  // row m, k-chunk [c*16, c*16+16)
    float s = s_lds[m];
    int kb = c * 16;
    int fb = (((m >> 5) * 8 + c) * 64 + (m & 31)) * 8;
#pragma unroll
    for (int u = 0; u < 2; u++) {
      unsigned uh[4], ul[4];
#pragma unroll
      for (int p = 0; p < 4; p++) {
        int k = kb + u * 8 + p * 2;
        unsigned short h0, l0, h1, l1;
        bsplit(eluf(fmaf(s, rwt0[k], tb0[k])), h0, l0);
        bsplit(eluf(fmaf(s, rwt0[k + 1], tb0[k + 1])), h1, l1);
        uh[p] = (unsigned)h0 | ((unsigned)h1 << 16);
        ul[p] = (unsigned)l0 | ((unsigned)l1 << 16);
      }
      *(uint4*)&csh[fb + u * 256] = make_uint4(uh[0], uh[1], uh[2], uh[3]);
      *(uint4*)&csl[fb + u * 256] = make_uint4(ul[0], ul[1], ul[2], ul[3]);
    }
  }
  __syncthreads();

  // gi = cs0 @ wih0^T : wave (mg,cb) does rows mg*32.. and gate cols cb*32..
  f32x16 acc[3] = {};
#pragma unroll
  for (int ks = 0; ks < 8; ks++) {
    bf16x8 ah = *(const bf16x8*)&csh[((mg * 8 + ks) * 64 + lane) * 8];
    bf16x8 al = *(const bf16x8*)&csl[((mg * 8 + ks) * 64 + lane) * 8];
#pragma unroll
    for (int g = 0; g < 3; g++) {
      int nt = g * 4 + cb;
      size_t base = (size_t)((nt * 8 + ks) * 64 + lane) * 8;
      bf16x8 bh = *(const bf16x8*)&w0ph[base];
      bf16x8 bl = *(const bf16x8*)&w0pl[base];
      MFMA3(acc[g], ah, al, bh, bl);
    }
  }

  // GRU epilogue (h = s broadcast), write x1 in split-bf16 frag layout
  const int jc = cb * 32 + (lane & 31);
  float bir = bih0[jc], biz = bih0[jc + 128], bin_ = bih0[jc + 256];
  float bhr = bhh0[jc], bhz = bhh0[jc + 128], bhn = bhh0[jc + 256];
  float rwr = rwh0[jc], rwz = rwh0[jc + 128], rwn = rwh0[jc + 256];
  const size_t tbase = (size_t)blockIdx.x * 8192;
  const int fj = ((mg * 8 + (cb * 2 + ((lane >> 4) & 1))) * 64 + ((lane >> 3) & 1) * 32) * 8 +
                 (lane & 7);
#pragma unroll
  for (int reg = 0; reg < 16; reg++) {
    int crow = (reg & 3) + 8 * (reg >> 2) + 4 * (lane >> 5);
    int m = mg * 32 + crow;
    float s = s_lds[m];
    float dd = deg_lds[m];
    float r = sigm(acc[0][reg] + bir + fmaf(s, rwr, bhr));
    float z = sigm(acc[1][reg] + biz + fmaf(s, rwz, bhz));
    float nn2 = ftanh(fmaf(r, fmaf(s, rwn, bhn), acc[2][reg] + bin_));
    float v = dd * ((1.f - z) * nn2 + z * s);
    unsigned short vh, vl;
    bsplit(v, vh, vl);
    unsigned pv = (unsigned)vh | ((unsigned)vl << 16);
    unsigned pu = __shfl_xor(pv, 1, 64);
    if ((lane & 1) == 0) {
      size_t f = tbase + fj + crow * 8;
      *(unsigned*)&x1h[f] = (pv & 0xFFFFu) | (pu << 16);
      *(unsigned*)&x1l[f] = (pv >> 16) | (pu & 0xFFFF0000u);
    }
  }
}

// ---------------- layer 1: M=64 nodes/block, 512 threads (8 waves = 2mg x 4cb) ----
// A-frags (h) load straight from global frag arrays -> no h staging, no h LDS.
// Gate-merge: r,z accumulate wih AND whh into the same C regs; n keeps gin/ghn.
__global__ __launch_bounds__(512, 4) void layer1_kernel(
    const unsigned short* __restrict__ x1h, const unsigned short* __restrict__ x1l,
    const float* __restrict__ tb1,
    const unsigned short* __restrict__ w1ph, const unsigned short* __restrict__ w1pl,
    const unsigned short* __restrict__ w2ph, const unsigned short* __restrict__ w2pl,
    const float* __restrict__ bih1, const float* __restrict__ bhh1,
    const int* __restrict__ deg, float* __restrict__ out) {
  __shared__ unsigned short cfh[8192];
  __shared__ unsigned short cfl[8192];
  __shared__ float deg_lds[64];

  const int tid = threadIdx.x;
  const int lane = tid & 63;
  const int wv = tid >> 6;
  const int mg = wv & 1;
  const int cb = wv >> 1;
  const int n0 = blockIdx.x * 64;
  const size_t tbase = (size_t)blockIdx.x * 8192;

  if (tid < 64) deg_lds[tid] = (float)deg[n0 + tid];

  // Phase A: aA[0]=r(whh), aA[1]=z(whh), aA[2]=ghn, aA[3]=t1 (w1)
  f32x16 aA[4] = {};
#pragma unroll
  for (int ks = 0; ks < 8; ks++) {
    bf16x8 ah = *(const bf16x8*)&x1h[tbase + ((mg * 8 + ks) * 64 + lane) * 8];
    bf16x8 al = *(const bf16x8*)&x1l[tbase + ((mg * 8 + ks) * 64 + lane) * 8];
    {
      size_t base = (size_t)((cb * 8 + ks) * 64 + lane) * 8;
      bf16x8 bh = *(const bf16x8*)&w1ph[base];
      bf16x8 bl = *(const bf16x8*)&w1pl[base];
      MFMA3(aA[3], ah, al, bh, bl);
    }
#pragma unroll
    for (int g = 0; g < 3; g++) {
      int nt = 12 + g * 4 + cb;
      size_t base = (size_t)((nt * 8 + ks) * 64 + lane) * 8;
      bf16x8 bh = *(const bf16x8*)&w2ph[base];
      bf16x8 bl = *(const bf16x8*)&w2pl[base];
      MFMA3(aA[g], ah, al, bh, bl);
    }
  }

  // cs = elu(t1 + tb1) -> split-bf16 LDS in frag layout (paired-lane b32 stores)
  {
    float tbj = tb1[cb * 32 + (lane & 31)];
    const int fj = ((mg * 8 + (cb * 2 + ((lane >> 4) & 1))) * 64 + ((lane >> 3) & 1) * 32) * 8 +
                   (lane & 7);
#pragma unroll
    for (int reg = 0; reg < 16; reg++) {
      int crow = (reg & 3) + 8 * (reg >> 2) + 4 * (lane >> 5);
      unsigned short vh, vl;
      bsplit(eluf(aA[3][reg] + tbj), vh, vl);
      unsigned pv = (unsigned)vh | ((unsigned)vl << 16);
      unsigned pu = __shfl_xor(pv, 1, 64);
      if ((lane & 1) == 0) {
        int f = fj + crow * 8;
        *(unsigned*)&cfh[f] = (pv & 0xFFFFu) | (pu << 16);
        *(unsigned*)&cfl[f] = (pv >> 16) | (pu & 0xFFFF0000u);
      }
    }
  }
  __syncthreads();

  // Phase B: gi r->aA[0], z->aA[1], n->aB[0]
  f32x16 aB[1] = {};
#pragma unroll
  for (int ks = 0; ks < 8; ks++) {
    bf16x8 ch = *(const bf16x8*)&cfh[((mg * 8 + ks) * 64 + lane) * 8];
    bf16x8 cl = *(const bf16x8*)&cfl[((mg * 8 + ks) * 64 + lane) * 8];
#pragma unroll
    for (int g = 0; g < 3; g++) {
      int nt = g * 4 + cb;
      size_t base = (size_t)((nt * 8 + ks) * 64 + lane) * 8;
      bf16x8 bh = *(const bf16x8*)&w2ph[base];
      bf16x8 bl = *(const bf16x8*)&w2pl[base];
      if (g == 0) { MFMA3(aA[0], ch, cl, bh, bl); }
      else if (g == 1) { MFMA3(aA[1], ch, cl, bh, bl); }
      else { MFMA3(aB[0], ch, cl, bh, bl); }
    }
  }

  // GRU epilogue + deg scale
  const int jc = cb * 32 + (lane & 31);
  float bir = bih1[jc], biz = bih1[jc + 128], bin_ = bih1[jc + 256];
  float bhr = bhh1[jc], bhz = bhh1[jc + 128], bhn = bhh1[jc + 256];
  const int fj = ((mg * 8 + (cb * 2 + ((lane >> 4) & 1))) * 64 + ((lane >> 3) & 1) * 32) * 8 +
                 (lane & 7);
#pragma unroll
  for (int reg = 0; reg < 16; reg++) {
    int crow = (reg & 3) + 8 * (reg >> 2) + 4 * (lane >> 5);
    int m = mg * 32 + crow;
    float dd = deg_lds[m];
    float r = sigm(aA[0][reg] + bir + bhr);
    float z = sigm(aA[1][reg] + biz + bhz);
    float nn2 = ftanh(fmaf(r, aA[2][reg] + bhn, aB[0][reg] + bin_));
    size_t f = tbase + fj + crow * 8;
    float hfull = (float)(*(const __bf16*)&x1h[f]) + (float)(*(const __bf16*)&x1l[f]);
    out[(size_t)(n0 + m) * 128 + jc] = dd * ((1.f - z) * nn2 + z * hfull);
  }
}

extern "C" void kernel_launch(void* const* d_in, const int* in_sizes, int n_in,
                              void* d_out, int out_size, void* d_ws, size_t ws_size,
                              hipStream_t stream) {
  const float* x     = (const float*)d_in[0];
  const int*   edge  = (const int*)d_in[1];
  const float* attw0 = (const float*)d_in[4];
  const float* attb0 = (const float*)d_in[5];
  const float* wih0  = (const float*)d_in[6];
  const float* whh0  = (const float*)d_in[7];
  const float* bih0  = (const float*)d_in[8];
  const float* bhh0  = (const float*)d_in[9];
  const float* attw1 = (const float*)d_in[12];
  const float* attb1 = (const float*)d_in[13];
  const float* wih1  = (const float*)d_in[14];
  const float* whh1  = (const float*)d_in[15];
  const float* bih1  = (const float*)d_in[16];
  const float* bhh1  = (const float*)d_in[17];

  float* ws = (float*)d_ws;
  unsigned short* x1h = (unsigned short*)ws;               // 25.6M shorts
  unsigned short* x1l = (unsigned short*)(ws + 12800000);  // 25.6M shorts
  int*   deg  = (int*)(ws + 25600000);
  float* rwt0 = ws + 25800000;
  float* rwh0 = ws + 25800128;
  unsigned short* wp = (unsigned short*)(ws + 25800512);
  unsigned short* w0ph = wp;             // 49152 shorts
  unsigned short* w0pl = wp + 49152;
  unsigned short* w1ph = wp + 98304;     // 16384
  unsigned short* w1pl = wp + 114688;
  unsigned short* w2ph = wp + 131072;    // 98304
  unsigned short* w2pl = wp + 229376;    // end 327680 shorts

  const int* dst = edge + NE;  // edge_index[1]

  hipMemsetAsync(deg, 0, NN * sizeof(int), stream);
  hist_kernel<<<(NE + 255) / 256, 256, 0, stream>>>(dst, deg);
  prep_kernel<<<128, 256, 0, stream>>>(attw0, whh0, rwt0, rwh0);
  pack_kernel<<<80, 256, 0, stream>>>(wih0, attw1, wih1, whh1,
                                      w0ph, w0pl, w1ph, w1pl, w2ph, w2pl);
  layer0_kernel<<<NN / 64, 512, 0, stream>>>(x, attb0, w0ph, w0pl, bih0, bhh0,
                                             rwt0, rwh0, deg, x1h, x1l);
  layer1_kernel<<<NN / 64, 512, 0, stream>>>(x1h, x1l, attb1, w1ph, w1pl, w2ph, w2pl,
                                             bih1, bhh1, deg, (float*)d_out);
}

// Round 4
// 450.422 us; speedup vs baseline: 1.0863x; 1.0520x over previous
//
#include <hip/hip_runtime.h>
#include <cmath>

#define NN 200000
#define NE 600000

typedef __bf16 bf16x8 __attribute__((ext_vector_type(8)));
typedef float f32x16 __attribute__((ext_vector_type(16)));

#define LOG2E 1.44269504088896340736f
__device__ __forceinline__ float fexp2(float x) { return __builtin_amdgcn_exp2f(x); }
__device__ __forceinline__ float frcp(float x) { return __builtin_amdgcn_rcpf(x); }
__device__ __forceinline__ float sigm(float v) { return frcp(1.0f + fexp2(-LOG2E * v)); }
__device__ __forceinline__ float ftanh(float v) {
  float t = fexp2(-2.0f * LOG2E * fabsf(v));
  float r = (1.0f - t) * frcp(1.0f + t);
  return __builtin_copysignf(r, v);
}
__device__ __forceinline__ float eluf(float v) { return v > 0.0f ? v : fexp2(LOG2E * v) - 1.0f; }

__device__ __forceinline__ unsigned short bfr(float f) {  // f32 -> bf16 RNE
  unsigned u = __float_as_uint(f);
  u += 0x7FFFu + ((u >> 16) & 1u);
  return (unsigned short)(u >> 16);
}
__device__ __forceinline__ void bsplit(float v, unsigned short& hi, unsigned short& lo) {
  unsigned short h = bfr(v);
  float hf = __uint_as_float(((unsigned)h) << 16);
  hi = h;
  lo = bfr(v - hf);
}

// ---------------- ws layout (float offsets) ----------------
// (x1 region now unused after fusion; offsets kept stable)
// deg(int) @25,600,000 ; rwt0[128] @25,800,000 ; rwh0[384] @25,800,128 ;
// packed weight frags (shorts) @float 25,800,512:
//   w0ph 49152 | w0pl 49152 | w1ph 16384 | w1pl 16384 | w2ph 98304 | w2pl 98304
// Frag order (32x32x16): frag[((nt*8+ks)*64+lane)*8+j] = W[nt*32+(lane&31)][ks*16+(lane>>5)*8+j]

__global__ __launch_bounds__(256) void hist_kernel(const int* __restrict__ dst,
                                                   int* __restrict__ deg) {
  int e = blockIdx.x * 256 + threadIdx.x;
  if (e < NE) atomicAdd(&deg[dst[e]], 1);
}

// one wave per row, coalesced float2 loads + shuffle reduce (512 rows total)
__global__ __launch_bounds__(256) void prep_kernel(const float* __restrict__ attw0,
                                                   const float* __restrict__ whh0,
                                                   float* __restrict__ rwt0,
                                                   float* __restrict__ rwh0) {
  int gw = blockIdx.x * 4 + (threadIdx.x >> 6);  // 0..511
  int lane = threadIdx.x & 63;
  const float* row = (gw < 128) ? (attw0 + (size_t)gw * 128)
                                : (whh0 + (size_t)(gw - 128) * 128);
  float2 v = ((const float2*)row)[lane];
  float a = v.x + v.y;
#pragma unroll
  for (int o = 1; o < 64; o <<= 1) a += __shfl_xor(a, o, 64);
  if (lane == 0) {
    if (gw < 128) rwt0[gw] = a;
    else rwh0[gw - 128] = a;
  }
}

// Pack weights into 32x32x16 MFMA B-fragment order, split hi/lo bf16.
__global__ __launch_bounds__(256) void pack_kernel(
    const float* __restrict__ wih0, const float* __restrict__ tw1,
    const float* __restrict__ wih1, const float* __restrict__ whh1,
    unsigned short* __restrict__ w0ph, unsigned short* __restrict__ w0pl,
    unsigned short* __restrict__ w1ph, unsigned short* __restrict__ w1pl,
    unsigned short* __restrict__ w2ph, unsigned short* __restrict__ w2pl) {
  int g = blockIdx.x * 256 + threadIdx.x;  // one 8-element lane-frag
  if (g >= 20480) return;
  unsigned short *PH, *PL;
  const float* row;
  int l;
  if (g < 6144) { l = g; PH = w0ph; PL = w0pl; }
  else if (g < 8192) { l = g - 6144; PH = w1ph; PL = w1pl; }
  else { l = g - 8192; PH = w2ph; PL = w2pl; }
  int lane = l & 63, ks = (l >> 6) & 7, nt = l >> 9;
  int n = nt * 32 + (lane & 31);
  int k0 = ks * 16 + (lane >> 5) * 8;
  if (g < 6144) row = wih0 + n * 128;
  else if (g < 8192) row = tw1 + n * 128;
  else row = (n < 384) ? wih1 + n * 128 : whh1 + (n - 384) * 128;
  unsigned uh[4], ul[4];
#pragma unroll
  for (int p = 0; p < 4; p++) {
    unsigned short ah, al, bh, bl;
    bsplit(row[k0 + 2 * p], ah, al);
    bsplit(row[k0 + 2 * p + 1], bh, bl);
    uh[p] = (unsigned)ah | ((unsigned)bh << 16);
    ul[p] = (unsigned)al | ((unsigned)bl << 16);
  }
  *(uint4*)&PH[l * 8] = make_uint4(uh[0], uh[1], uh[2], uh[3]);
  *(uint4*)&PL[l * 8] = make_uint4(ul[0], ul[1], ul[2], ul[3]);
}

#define MFMA3(accv, ah, al, bh, bl)                                          \
  accv = __builtin_amdgcn_mfma_f32_32x32x16_bf16(ah, bh, accv, 0, 0, 0);     \
  accv = __builtin_amdgcn_mfma_f32_32x32x16_bf16(ah, bl, accv, 0, 0, 0);     \
  accv = __builtin_amdgcn_mfma_f32_32x32x16_bf16(al, bh, accv, 0, 0, 0);

// ---------------- fused both layers: M=64 nodes/block, 512 threads (8 waves) ------
// Wave (mg = wv&1, cb = wv>>2... wv>>1): rows mg*32..+32, cols cb*32..+32.
// h (= x1 tile) never leaves the block: kept as split-bf16 frags in LDS.
__global__ __launch_bounds__(512, 4) void fused_kernel(
    const float* __restrict__ x,
    const float* __restrict__ tb0, const float* __restrict__ tb1,
    const unsigned short* __restrict__ w0ph, const unsigned short* __restrict__ w0pl,
    const unsigned short* __restrict__ w1ph, const unsigned short* __restrict__ w1pl,
    const unsigned short* __restrict__ w2ph, const unsigned short* __restrict__ w2pl,
    const float* __restrict__ bih0, const float* __restrict__ bhh0,
    const float* __restrict__ rwt0, const float* __restrict__ rwh0,
    const float* __restrict__ bih1, const float* __restrict__ bhh1,
    const int* __restrict__ deg, float* __restrict__ out) {
  extern __shared__ unsigned short smem[];
  unsigned short* csh = smem;            // 8192 shorts (cs0, later reused for cs1)
  unsigned short* csl = smem + 8192;     // 8192
  unsigned short* hfh = smem + 16384;    // 8192 (h frags, live to the end)
  unsigned short* hfl = smem + 24576;    // 8192  -> 65536 B dynamic
  __shared__ float s_lds[64];
  __shared__ float deg_lds[64];

  const int tid = threadIdx.x;
  const int lane = tid & 63;
  const int wv = tid >> 6;
  const int mg = wv & 1;
  const int cb = wv >> 1;
  const int n0 = blockIdx.x * 64;

  if (tid < 64) deg_lds[tid] = (float)deg[n0 + tid];

  // s_m = rowsum(x[m])
  {
    int m = tid >> 3, c = (tid & 7) * 16;
    const float4* xr = (const float4*)(x + (size_t)(n0 + m) * 128 + c);
    float a = 0.f;
#pragma unroll
    for (int q = 0; q < 4; q++) { float4 v = xr[q]; a += v.x + v.y + v.z + v.w; }
#pragma unroll
    for (int o = 1; o < 8; o <<= 1) a += __shfl_xor(a, o, 64);
    if ((tid & 7) == 0) s_lds[m] = a;
  }
  __syncthreads();

  // cs0 -> split-bf16 LDS in 32x32 A-frag layout (lane-linear, conflict-free)
  {
    int m = lane, c = wv;  // row m, k-chunk [c*16, c*16+16)
    float s = s_lds[m];
    int kb = c * 16;
    int fb = (((m >> 5) * 8 + c) * 64 + (m & 31)) * 8;
#pragma unroll
    for (int u = 0; u < 2; u++) {
      unsigned uh[4], ul[4];
#pragma unroll
      for (int p = 0; p < 4; p++) {
        int k = kb + u * 8 + p * 2;
        unsigned short h0, l0, h1, l1;
        bsplit(eluf(fmaf(s, rwt0[k], tb0[k])), h0, l0);
        bsplit(eluf(fmaf(s, rwt0[k + 1], tb0[k + 1])), h1, l1);
        uh[p] = (unsigned)h0 | ((unsigned)h1 << 16);
        ul[p] = (unsigned)l0 | ((unsigned)l1 << 16);
      }
      *(uint4*)&csh[fb + u * 256] = make_uint4(uh[0], uh[1], uh[2], uh[3]);
      *(uint4*)&csl[fb + u * 256] = make_uint4(ul[0], ul[1], ul[2], ul[3]);
    }
  }
  __syncthreads();

  const int jc = cb * 32 + (lane & 31);
  const int fj = ((mg * 8 + (cb * 2 + ((lane >> 4) & 1))) * 64 + ((lane >> 3) & 1) * 32) * 8 +
                 (lane & 7);

  // ---- layer 0 GEMM: gi0 = cs0 @ wih0^T ----
  f32x16 g0[3] = {};
#pragma unroll
  for (int ks = 0; ks < 8; ks++) {
    bf16x8 ah = *(const bf16x8*)&csh[((mg * 8 + ks) * 64 + lane) * 8];
    bf16x8 al = *(const bf16x8*)&csl[((mg * 8 + ks) * 64 + lane) * 8];
#pragma unroll
    for (int g = 0; g < 3; g++) {
      int nt = g * 4 + cb;
      size_t base = (size_t)((nt * 8 + ks) * 64 + lane) * 8;
      bf16x8 bh = *(const bf16x8*)&w0ph[base];
      bf16x8 bl = *(const bf16x8*)&w0pl[base];
      MFMA3(g0[g], ah, al, bh, bl);
    }
  }

  // ---- GRU0 epilogue (h_s = s broadcast): h -> split-bf16 frags in LDS ----
  {
    float bir = bih0[jc], biz = bih0[jc + 128], bin_ = bih0[jc + 256];
    float bhr = bhh0[jc], bhz = bhh0[jc + 128], bhn = bhh0[jc + 256];
    float rwr = rwh0[jc], rwz = rwh0[jc + 128], rwn = rwh0[jc + 256];
#pragma unroll
    for (int reg = 0; reg < 16; reg++) {
      int crow = (reg & 3) + 8 * (reg >> 2) + 4 * (lane >> 5);
      int m = mg * 32 + crow;
      float s = s_lds[m];
      float dd = deg_lds[m];
      float r = sigm(g0[0][reg] + bir + fmaf(s, rwr, bhr));
      float z = sigm(g0[1][reg] + biz + fmaf(s, rwz, bhz));
      float nn2 = ftanh(fmaf(r, fmaf(s, rwn, bhn), g0[2][reg] + bin_));
      float v = dd * ((1.f - z) * nn2 + z * s);
      unsigned short vh, vl;
      bsplit(v, vh, vl);
      unsigned pv = (unsigned)vh | ((unsigned)vl << 16);
      unsigned pu = __shfl_xor(pv, 1, 64);
      if ((lane & 1) == 0) {
        int f = fj + crow * 8;
        *(unsigned*)&hfh[f] = (pv & 0xFFFFu) | (pu << 16);
        *(unsigned*)&hfl[f] = (pv >> 16) | (pu & 0xFFFF0000u);
      }
    }
  }
  // guards: (a) h frags written before any wave reads them; (b) all cs0 reads
  // (GEMM0) done before cs1 overwrites csh/csl below.
  __syncthreads();

  // ---- layer 1, t1 chain: t1 = h @ tw1^T (16 acc regs) ----
  f32x16 a1 = {};
#pragma unroll
  for (int ks = 0; ks < 8; ks++) {
    bf16x8 ah = *(const bf16x8*)&hfh[((mg * 8 + ks) * 64 + lane) * 8];
    bf16x8 al = *(const bf16x8*)&hfl[((mg * 8 + ks) * 64 + lane) * 8];
    size_t base = (size_t)((cb * 8 + ks) * 64 + lane) * 8;
    bf16x8 bh = *(const bf16x8*)&w1ph[base];
    bf16x8 bl = *(const bf16x8*)&w1pl[base];
    MFMA3(a1, ah, al, bh, bl);
  }

  // cs1 = elu(t1 + tb1) -> split-bf16 LDS (reusing cs0 buffers)
  {
    float tbj = tb1[jc];
#pragma unroll
    for (int reg = 0; reg < 16; reg++) {
      int crow = (reg & 3) + 8 * (reg >> 2) + 4 * (lane >> 5);
      unsigned short vh, vl;
      bsplit(eluf(a1[reg] + tbj), vh, vl);
      unsigned pv = (unsigned)vh | ((unsigned)vl << 16);
      unsigned pu = __shfl_xor(pv, 1, 64);
      if ((lane & 1) == 0) {
        int f = fj + crow * 8;
        *(unsigned*)&csh[f] = (pv & 0xFFFFu) | (pu << 16);
        *(unsigned*)&csl[f] = (pv >> 16) | (pu & 0xFFFF0000u);
      }
    }
  }
  __syncthreads();

  // ---- layer 1 main: gh (h @ whh1^T) and gi (cs1 @ wih1^T) interleaved.
  // Gate-merge: r,z accumulate both GEMMs into the same C regs; n stays split.
  f32x16 aR = {}, aZ = {}, aGHN = {}, aGIN = {};
#pragma unroll
  for (int ks = 0; ks < 8; ks++) {
    bf16x8 xh = *(const bf16x8*)&hfh[((mg * 8 + ks) * 64 + lane) * 8];
    bf16x8 xl = *(const bf16x8*)&hfl[((mg * 8 + ks) * 64 + lane) * 8];
    bf16x8 ch = *(const bf16x8*)&csh[((mg * 8 + ks) * 64 + lane) * 8];
    bf16x8 cl = *(const bf16x8*)&csl[((mg * 8 + ks) * 64 + lane) * 8];
#pragma unroll
    for (int g = 0; g < 3; g++) {
      // gh: whh1 tiles at nt = 12 + g*4 + cb
      {
        size_t base = (size_t)(((12 + g * 4 + cb) * 8 + ks) * 64 + lane) * 8;
        bf16x8 bh = *(const bf16x8*)&w2ph[base];
        bf16x8 bl = *(const bf16x8*)&w2pl[base];
        if (g == 0) { MFMA3(aR, xh, xl, bh, bl); }
        else if (g == 1) { MFMA3(aZ, xh, xl, bh, bl); }
        else { MFMA3(aGHN, xh, xl, bh, bl); }
      }
      // gi: wih1 tiles at nt = g*4 + cb
      {
        size_t base = (size_t)(((g * 4 + cb) * 8 + ks) * 64 + lane) * 8;
        bf16x8 bh = *(const bf16x8*)&w2ph[base];
        bf16x8 bl = *(const bf16x8*)&w2pl[base];
        if (g == 0) { MFMA3(aR, ch, cl, bh, bl); }
        else if (g == 1) { MFMA3(aZ, ch, cl, bh, bl); }
        else { MFMA3(aGIN, ch, cl, bh, bl); }
      }
    }
  }

  // ---- GRU1 epilogue + deg scale ----
  {
    float bir = bih1[jc], biz = bih1[jc + 128], bin_ = bih1[jc + 256];
    float bhr = bhh1[jc], bhz = bhh1[jc + 128], bhn = bhh1[jc + 256];
#pragma unroll
    for (int reg = 0; reg < 16; reg++) {
      int crow = (reg & 3) + 8 * (reg >> 2) + 4 * (lane >> 5);
      int m = mg * 32 + crow;
      float dd = deg_lds[m];
      float r = sigm(aR[reg] + bir + bhr);
      float z = sigm(aZ[reg] + biz + bhz);
      float nn2 = ftanh(fmaf(r, aGHN[reg] + bhn, aGIN[reg] + bin_));
      int f = fj + crow * 8;
      float hfull = (float)(*(const __bf16*)&hfh[f]) + (float)(*(const __bf16*)&hfl[f]);
      out[(size_t)(n0 + m) * 128 + jc] = dd * ((1.f - z) * nn2 + z * hfull);
    }
  }
}

extern "C" void kernel_launch(void* const* d_in, const int* in_sizes, int n_in,
                              void* d_out, int out_size, void* d_ws, size_t ws_size,
                              hipStream_t stream) {
  const float* x     = (const float*)d_in[0];
  const int*   edge  = (const int*)d_in[1];
  const float* attw0 = (const float*)d_in[4];
  const float* attb0 = (const float*)d_in[5];
  const float* wih0  = (const float*)d_in[6];
  const float* whh0  = (const float*)d_in[7];
  const float* bih0  = (const float*)d_in[8];
  const float* bhh0  = (const float*)d_in[9];
  const float* attw1 = (const float*)d_in[12];
  const float* attb1 = (const float*)d_in[13];
  const float* wih1  = (const float*)d_in[14];
  const float* whh1  = (const float*)d_in[15];
  const float* bih1  = (const float*)d_in[16];
  const float* bhh1  = (const float*)d_in[17];

  float* ws = (float*)d_ws;
  int*   deg  = (int*)(ws + 25600000);
  float* rwt0 = ws + 25800000;
  float* rwh0 = ws + 25800128;
  unsigned short* wp = (unsigned short*)(ws + 25800512);
  unsigned short* w0ph = wp;             // 49152 shorts
  unsigned short* w0pl = wp + 49152;
  unsigned short* w1ph = wp + 98304;     // 16384
  unsigned short* w1pl = wp + 114688;
  unsigned short* w2ph = wp + 131072;    // 98304
  unsigned short* w2pl = wp + 229376;    // end 327680 shorts

  const int* dst = edge + NE;  // edge_index[1]

  static bool attr_done = false;
  if (!attr_done) {
    hipFuncSetAttribute(reinterpret_cast<const void*>(fused_kernel),
                        hipFuncAttributeMaxDynamicSharedMemorySize, 65536);
    attr_done = true;
  }

  hipMemsetAsync(deg, 0, NN * sizeof(int), stream);
  hist_kernel<<<(NE + 255) / 256, 256, 0, stream>>>(dst, deg);
  prep_kernel<<<128, 256, 0, stream>>>(attw0, whh0, rwt0, rwh0);
  pack_kernel<<<80, 256, 0, stream>>>(wih0, attw1, wih1, whh1,
                                      w0ph, w0pl, w1ph, w1pl, w2ph, w2pl);
  fused_kernel<<<NN / 64, 512, 65536, stream>>>(
      x, attb0, attb1, w0ph, w0pl, w1ph, w1pl, w2ph, w2pl,
      bih0, bhh0, rwt0, rwh0, bih1, bhh1, deg, (float*)d_out);
}